// Round 1
// baseline (264.217 us; speedup 1.0000x reference)
//
#include <hip/hip_runtime.h>

namespace {

constexpr int kW = 640;
constexpr int kH = 360;
constexpr int kN = kW * kH;      // 230400
constexpr int kT = 1000;         // RANSAC iterations
constexpr unsigned kSpan = 230400u;

struct __align__(16) Accum {
  double sdx2, sdy2, sdz2, sdl2; // masked sum of squares
  double sum_zc;                 // masked sum of zc
  int cnt;                       // |m|
  int icnt;                      // inlier count for best plane
  unsigned maxkey;               // ordered-key max of nan_cloud
  unsigned zmaxkey;              // ordered-key max of masked zc
  unsigned zminkey;              // ordered-key min of masked zc
  unsigned pad;
  float4 best_plane;             // a,b,c,kk
  float4 rot;                    // R20,R21,R22, trans_z=d/c
};

__device__ __forceinline__ unsigned fkey(float f) {
  unsigned u = __float_as_uint(f);
  return (u & 0x80000000u) ? ~u : (u | 0x80000000u);
}
__device__ __forceinline__ float funkey(unsigned k) {
  unsigned u = (k & 0x80000000u) ? (k & 0x7FFFFFFFu) : ~k;
  return __uint_as_float(u);
}

__device__ __forceinline__ unsigned rotl32(unsigned v, int r) {
  return (v << r) | (v >> (32 - r));
}

// Threefry-2x32, 20 rounds, key = (0, 42)  [jax.random.key(42)]
__device__ __forceinline__ void threefry(unsigned c0, unsigned c1,
                                         unsigned& o0, unsigned& o1) {
  const unsigned ks0 = 0u, ks1 = 42u, ks2 = 0x1BD11BDAu ^ 0u ^ 42u;
  unsigned x0 = c0 + ks0, x1 = c1 + ks1;
#define TFR(r) { x0 += x1; x1 = rotl32(x1, (r)); x1 ^= x0; }
  TFR(13) TFR(15) TFR(26) TFR(6)
  x0 += ks1; x1 += ks2 + 1u;
  TFR(17) TFR(29) TFR(16) TFR(24)
  x0 += ks2; x1 += ks0 + 2u;
  TFR(13) TFR(15) TFR(26) TFR(6)
  x0 += ks0; x1 += ks1 + 3u;
  TFR(17) TFR(29) TFR(16) TFR(24)
  x0 += ks1; x1 += ks2 + 4u;
  TFR(13) TFR(15) TFR(26) TFR(6)
  x0 += ks2; x1 += ks0 + 5u;
#undef TFR
  o0 = x0; o1 = x1;
}

// Mirrors reference: z=d/1000 ; x=z*(c-CX)/FX ; *1000 ; ==0 -> 1e-7
__device__ __forceinline__ void pix_coords(float d, int row, int col, bool& valid,
                                           float& x, float& y, float& z) {
  valid = (d > 0.0f) && (d < 65535.0f);
  float z0 = d / 1000.0f;
  float x0 = z0 * ((float)col - 334.081f) / 460.585f;
  float y0 = z0 * ((float)row - 169.808f) / 460.268f;
  x = x0 * 1000.0f;
  y = y0 * 1000.0f;
  z = z0 * 1000.0f;
  if (x == 0.0f) x = 1e-7f;
  if (y == 0.0f) y = 1e-7f;
  if (z == 0.0f) z = 1e-7f;
}

__device__ __forceinline__ float get_thresh(int ep) {
  return (float)fmax(0.025 - 0.001 * (double)ep, 0.005);
}

__global__ __launch_bounds__(1024) void init_kernel(Accum* acc, int* counts) {
  int t = threadIdx.x;
  if (t < kT) counts[t] = 0;
  if (t == 0) {
    acc->sdx2 = 0.0; acc->sdy2 = 0.0; acc->sdz2 = 0.0; acc->sdl2 = 0.0;
    acc->sum_zc = 0.0;
    acc->cnt = 0; acc->icnt = 0;
    acc->maxkey = 0u;
    acc->zmaxkey = 0u;
    acc->zminkey = 0xFFFFFFFFu;
  }
}

__global__ __launch_bounds__(256) void stats_kernel(const float* __restrict__ real,
                                                    const float* __restrict__ fake,
                                                    Accum* __restrict__ acc) {
  int i = blockIdx.x * 256 + threadIdx.x;  // grid covers exactly kN
  int row = i / kW;
  int col = i - row * kW;
  float rd = real[i], fd = fake[i];
  bool vr, vf;
  float rx, ry, rz, fx, fy, fz;
  pix_coords(rd, row, col, vr, rx, ry, rz);
  pix_coords(fd, row, col, vf, fx, fy, fz);
  bool m = vr && vf;
  double dx2 = 0.0, dy2 = 0.0, dz2 = 0.0, dl2 = 0.0;
  int c = 0;
  if (m) {
    float dx = rx - fx, dy = ry - fy, dz = rz - fz;
    dx2 = (double)dx * (double)dx;
    dy2 = (double)dy * (double)dy;
    dz2 = (double)dz * (double)dz;
    double dl = log(fabs((double)rz)) - log(fabs((double)fz));
    dl2 = dl * dl;
    c = 1;
  }
  float mx = vf ? fmaxf(fmaxf(fx, fy), fz) : 0.0f;  // nan_cloud candidate max

  // wave64 reduce
  for (int o = 32; o; o >>= 1) {
    dx2 += __shfl_down(dx2, o);
    dy2 += __shfl_down(dy2, o);
    dz2 += __shfl_down(dz2, o);
    dl2 += __shfl_down(dl2, o);
    c   += __shfl_down(c, o);
    mx = fmaxf(mx, __shfl_down(mx, o));
  }
  __shared__ double s0[4], s1[4], s2[4], s3[4];
  __shared__ int sc[4];
  __shared__ float sm[4];
  int lane = threadIdx.x & 63, wid = threadIdx.x >> 6;
  if (lane == 0) { s0[wid] = dx2; s1[wid] = dy2; s2[wid] = dz2; s3[wid] = dl2;
                   sc[wid] = c; sm[wid] = mx; }
  __syncthreads();
  if (threadIdx.x == 0) {
    atomicAdd(&acc->sdx2, s0[0] + s0[1] + s0[2] + s0[3]);
    atomicAdd(&acc->sdy2, s1[0] + s1[1] + s1[2] + s1[3]);
    atomicAdd(&acc->sdz2, s2[0] + s2[1] + s2[2] + s2[3]);
    atomicAdd(&acc->sdl2, s3[0] + s3[1] + s3[2] + s3[3]);
    atomicAdd(&acc->cnt, sc[0] + sc[1] + sc[2] + sc[3]);
    float bm = fmaxf(fmaxf(sm[0], sm[1]), fmaxf(sm[2], sm[3]));
    atomicMax(&acc->maxkey, fkey(bm));
  }
}

__global__ __launch_bounds__(256) void pts_kernel(const float* __restrict__ fake,
                                                  const Accum* __restrict__ acc,
                                                  float4* __restrict__ pts) {
  int i = blockIdx.x * 256 + threadIdx.x;
  float maxv = funkey(acc->maxkey);
  int row = i / kW;
  int col = i - row * kW;
  bool vf; float fx, fy, fz;
  pix_coords(fake[i], row, col, vf, fx, fy, fz);
  float px = vf ? fx : 0.0f;   // nan_cloud: NaN -> 0
  float py = vf ? fy : 0.0f;
  float pz = vf ? fz : 0.0f;
  pts[i] = make_float4(px / maxv, py / maxv, pz / maxv, 0.0f);
}

__global__ __launch_bounds__(64) void planes_kernel(const float4* __restrict__ pts,
                                                    float4* __restrict__ planes) {
  int t = blockIdx.x * 64 + threadIdx.x;
  if (t >= kT) return;
  float3 P[3];
#pragma unroll
  for (int j = 0; j < 3; j++) {
    unsigned p = 3u * (unsigned)t + (unsigned)j;
    unsigned o0, o1;
    threefry(p, p + 3000u, o0, o1);       // counts (p, p+3000)
    unsigned idx = o1 % kSpan;            // multiplier wraps to 0 => lower % span
    float4 q = pts[idx];
    P[j] = make_float3(q.x, q.y, q.z);
  }
  float ax = P[1].x - P[0].x, ay = P[1].y - P[0].y, az = P[1].z - P[0].z;
  float bx = P[2].x - P[0].x, by = P[2].y - P[0].y, bz = P[2].z - P[0].z;
  float nx = ay * bz - az * by;
  float ny = az * bx - ax * bz;
  float nz = ax * by - ay * bx;
  float nn = sqrtf(nx * nx + ny * ny + nz * nz);
  nx /= nn; ny /= nn; nz /= nn;
  float kk = -(nx * P[1].x + ny * P[1].y + nz * P[1].z);
  planes[t] = make_float4(nx, ny, nz, kk);
}

// Each thread owns 4 planes in registers; block stages 256 points in LDS.
__global__ __launch_bounds__(256) void count_kernel(const float4* __restrict__ pts,
                                                    const float4* __restrict__ planes,
                                                    int* __restrict__ counts,
                                                    const int* __restrict__ epoch) {
  __shared__ float4 spts[256];
  int tid = threadIdx.x;
  float th = get_thresh(*epoch);
  int base = tid * 4;
  float4 pl0 = (base + 0 < kT) ? planes[base + 0] : make_float4(0.f, 0.f, 0.f, 1e30f);
  float4 pl1 = (base + 1 < kT) ? planes[base + 1] : make_float4(0.f, 0.f, 0.f, 1e30f);
  float4 pl2 = (base + 2 < kT) ? planes[base + 2] : make_float4(0.f, 0.f, 0.f, 1e30f);
  float4 pl3 = (base + 3 < kT) ? planes[base + 3] : make_float4(0.f, 0.f, 0.f, 1e30f);
  int c0 = 0, c1 = 0, c2 = 0, c3 = 0;
  int start = blockIdx.x * 256;
  spts[tid] = pts[start + tid];
  __syncthreads();
#pragma unroll 8
  for (int s = 0; s < 256; s++) {
    float4 q = spts[s];
    float d0 = fmaf(q.x, pl0.x, fmaf(q.y, pl0.y, fmaf(q.z, pl0.z, pl0.w)));
    float d1 = fmaf(q.x, pl1.x, fmaf(q.y, pl1.y, fmaf(q.z, pl1.z, pl1.w)));
    float d2 = fmaf(q.x, pl2.x, fmaf(q.y, pl2.y, fmaf(q.z, pl2.z, pl2.w)));
    float d3 = fmaf(q.x, pl3.x, fmaf(q.y, pl3.y, fmaf(q.z, pl3.z, pl3.w)));
    c0 += (fabsf(d0) <= th) ? 1 : 0;
    c1 += (fabsf(d1) <= th) ? 1 : 0;
    c2 += (fabsf(d2) <= th) ? 1 : 0;
    c3 += (fabsf(d3) <= th) ? 1 : 0;
  }
  if (base + 0 < kT) atomicAdd(&counts[base + 0], c0);
  if (base + 1 < kT) atomicAdd(&counts[base + 1], c1);
  if (base + 2 < kT) atomicAdd(&counts[base + 2], c2);
  if (base + 3 < kT) atomicAdd(&counts[base + 3], c3);
}

__global__ __launch_bounds__(1024) void select_kernel(const int* __restrict__ counts,
                                                      const float4* __restrict__ planes,
                                                      Accum* __restrict__ acc) {
  __shared__ int ssc[1024];
  __shared__ int sidx[1024];
  int t = threadIdx.x;
  int sc = -2;
  if (t < kT) {
    int c = counts[t];
    sc = (c > 5000) ? c : -1;   // MIN_POINTS=5000, strict >
  }
  ssc[t] = sc;
  sidx[t] = t;
  __syncthreads();
  for (int off = 512; off; off >>= 1) {
    if (t < off) {
      // argmax, first occurrence on ties
      if (ssc[t + off] > ssc[t] ||
          (ssc[t + off] == ssc[t] && sidx[t + off] < sidx[t])) {
        ssc[t] = ssc[t + off];
        sidx[t] = sidx[t + off];
      }
    }
    __syncthreads();
  }
  if (t == 0) {
    int best = sidx[0];
    float4 pl = planes[best];
    acc->best_plane = pl;
    float a = pl.x, b = pl.y, c = pl.z, d = pl.w;
    float n2 = a * a + b * b + c * c;
    float cos_t = c / sqrtf(n2);
    float sin_t = sqrtf((a * a + b * b) / n2);
    float sab = sqrtf(a * a + b * b);
    float u1 = b / sab;
    float u2 = -a / sab;
    // R row 2: [-u2*sin_t, u1*sin_t, cos_t]; trans_z = d/c
    acc->rot = make_float4(-u2 * sin_t, u1 * sin_t, cos_t, d / c);
  }
}

__global__ __launch_bounds__(256) void zc_kernel(const float4* __restrict__ pts,
                                                 Accum* __restrict__ acc,
                                                 const int* __restrict__ epoch) {
  int i = blockIdx.x * 256 + threadIdx.x;
  float th = get_thresh(*epoch);
  float4 bp = acc->best_plane;
  float4 rot = acc->rot;
  float4 p = pts[i];
  // Same fmaf chain as count_kernel -> identical inlier mask
  float dist = fmaf(p.x, bp.x, fmaf(p.y, bp.y, fmaf(p.z, bp.z, bp.w)));
  bool m = fabsf(dist) <= th;
  float zc = fmaf(p.x, rot.x, fmaf(p.y, rot.y, (p.z + rot.w) * rot.z));
  double sz = m ? (double)zc : 0.0;
  int ic = m ? 1 : 0;
  float zmx = m ? zc : -INFINITY;
  float zmn = m ? zc : INFINITY;
  for (int o = 32; o; o >>= 1) {
    sz += __shfl_down(sz, o);
    ic += __shfl_down(ic, o);
    zmx = fmaxf(zmx, __shfl_down(zmx, o));
    zmn = fminf(zmn, __shfl_down(zmn, o));
  }
  __shared__ double ssz[4];
  __shared__ int sic[4];
  __shared__ float smx[4], smn[4];
  int lane = threadIdx.x & 63, wid = threadIdx.x >> 6;
  if (lane == 0) { ssz[wid] = sz; sic[wid] = ic; smx[wid] = zmx; smn[wid] = zmn; }
  __syncthreads();
  if (threadIdx.x == 0) {
    atomicAdd(&acc->sum_zc, ssz[0] + ssz[1] + ssz[2] + ssz[3]);
    atomicAdd(&acc->icnt, sic[0] + sic[1] + sic[2] + sic[3]);
    float bmx = fmaxf(fmaxf(smx[0], smx[1]), fmaxf(smx[2], smx[3]));
    float bmn = fminf(fminf(smn[0], smn[1]), fminf(smn[2], smn[3]));
    atomicMax(&acc->zmaxkey, fkey(bmx));
    atomicMin(&acc->zminkey, fkey(bmn));
  }
}

__global__ void final_kernel(const Accum* __restrict__ acc, float* __restrict__ out) {
  double cnt = acc->cnt > 0 ? (double)acc->cnt : 1.0;
  double lossX = sqrt(acc->sdx2 / cnt);
  double lossY = sqrt(acc->sdy2 / cnt);
  double lossZ = sqrt(acc->sdz2 / cnt);
  double rmse_log = 10000.0 * sqrt(acc->sdl2 / cnt);
  double loss17 = rmse_log * fabs(10.0 * (3.0 - exp(lossX) - exp(lossY) - exp(lossZ)));
  int ic = acc->icnt;
  double below, above;
  if (ic > 0) {
    double icnt = (double)ic;
    double mean = acc->sum_zc / icnt;
    double zmax = (double)funkey(acc->zmaxkey);
    double zmin = (double)funkey(acc->zminkey);
    below = zmax - mean;   // sum(|zc - zmax|)/icnt, all zc <= zmax
    above = mean - zmin;   // sum(|zc - zmin|)/icnt
  } else {
    below = 0.0; above = 0.0;
  }
  if (above == 0.0) above = 1e-7;
  double pmdg = 1000.0 * (above + below);
  double loss_curv = loss17 + pmdg;
  out[0] = (float)rmse_log;
  out[1] = (float)lossX;
  out[2] = (float)lossY;
  out[3] = (float)lossZ;
  out[4] = (float)pmdg;
  out[5] = (float)loss17;
  out[6] = (float)loss_curv;
}

}  // namespace

extern "C" void kernel_launch(void* const* d_in, const int* in_sizes, int n_in,
                              void* d_out, int out_size, void* d_ws, size_t ws_size,
                              hipStream_t stream) {
  (void)in_sizes; (void)n_in; (void)out_size; (void)ws_size;
  const float* fake = (const float*)d_in[0];
  const float* real = (const float*)d_in[1];
  const int* epoch = (const int*)d_in[2];
  float* out = (float*)d_out;

  char* ws = (char*)d_ws;
  Accum* acc = (Accum*)ws;                       // 96 B @ 0
  int* counts = (int*)(ws + 128);                // 4000 B
  float4* planes = (float4*)(ws + 4224);         // 16000 B
  float4* pts = (float4*)(ws + 20480);           // 3.69 MB

  constexpr int nblk = kN / 256;                 // 900, exact

  init_kernel<<<1, 1024, 0, stream>>>(acc, counts);
  stats_kernel<<<nblk, 256, 0, stream>>>(real, fake, acc);
  pts_kernel<<<nblk, 256, 0, stream>>>(fake, acc, pts);
  planes_kernel<<<(kT + 63) / 64, 64, 0, stream>>>(pts, planes);
  count_kernel<<<nblk, 256, 0, stream>>>(pts, planes, counts, epoch);
  select_kernel<<<1, 1024, 0, stream>>>(counts, planes, acc);
  zc_kernel<<<nblk, 256, 0, stream>>>(pts, acc, epoch);
  final_kernel<<<1, 1, 0, stream>>>(acc, out);
}